// Round 1
// baseline (77.056 us; speedup 1.0000x reference)
//
#include <hip/hip_runtime.h>
#include <hip/hip_bf16.h>
#include <math.h>

// Problem constants (from reference): x shape (32, 512, 56, 56) fp32,
// groups shape (G, 4) int32 (partition of channels, -1 padded).
#define NB 32
#define CC 512
#define HW 3136       // 56*56
#define HW4 784       // HW/4, float4 granularity
#define SMAX 4

// One thread: one (n, group, pixel4). Reads up to 4 channels x float4,
// per-lane argmax (strict >, first occurrence wins like jnp.argmax),
// writes winner value / zeros. Groups partition C, so every output
// element is written exactly once.
__global__ __launch_bounds__(256) void cgm_kernel(
    const float* __restrict__ x,
    const int* __restrict__ groups,
    float* __restrict__ out,
    int G)
{
    int idx = blockIdx.x * blockDim.x + threadIdx.x;
    int total = NB * G * HW4;
    if (idx >= total) return;

    int p4 = idx % HW4;          // which float4 within the HW plane
    int ng = idx / HW4;
    int g  = ng % G;
    int n  = ng / G;

    // group channel indices (wave-mostly-uniform, tiny, L2-resident)
    int ch0 = groups[g * SMAX + 0];
    int ch1 = groups[g * SMAX + 1];
    int ch2 = groups[g * SMAX + 2];
    int ch3 = groups[g * SMAX + 3];
    int ch[SMAX] = {ch0, ch1, ch2, ch3};

    size_t nbase = (size_t)n * CC * HW + (size_t)p4 * 4;

    float v[SMAX][4];
#pragma unroll
    for (int s = 0; s < SMAX; ++s) {
        if (ch[s] >= 0) {
            float4 t = *reinterpret_cast<const float4*>(x + nbase + (size_t)ch[s] * HW);
            v[s][0] = t.x; v[s][1] = t.y; v[s][2] = t.z; v[s][3] = t.w;
        } else {
#pragma unroll
            for (int j = 0; j < 4; ++j) v[s][j] = -INFINITY;
        }
    }

    // per-lane argmax over s (first occurrence of max wins)
    int win[4];
#pragma unroll
    for (int j = 0; j < 4; ++j) {
        float best = v[0][j];
        int   wi   = 0;
#pragma unroll
        for (int s = 1; s < SMAX; ++s) {
            if (v[s][j] > best) { best = v[s][j]; wi = s; }
        }
        win[j] = wi;
    }

#pragma unroll
    for (int s = 0; s < SMAX; ++s) {
        if (ch[s] >= 0) {
            float4 o;
            o.x = (win[0] == s) ? v[s][0] : 0.0f;
            o.y = (win[1] == s) ? v[s][1] : 0.0f;
            o.z = (win[2] == s) ? v[s][2] : 0.0f;
            o.w = (win[3] == s) ? v[s][3] : 0.0f;
            *reinterpret_cast<float4*>(out + nbase + (size_t)ch[s] * HW) = o;
        }
    }
}

extern "C" void kernel_launch(void* const* d_in, const int* in_sizes, int n_in,
                              void* d_out, int out_size, void* d_ws, size_t ws_size,
                              hipStream_t stream) {
    const float* x      = (const float*)d_in[0];
    const int*   groups = (const int*)d_in[1];
    float*       out    = (float*)d_out;

    int G = in_sizes[1] / SMAX;   // 147 for this problem
    int total = NB * G * HW4;     // 3,687,936
    int block = 256;
    int grid = (total + block - 1) / block;

    cgm_kernel<<<grid, block, 0, stream>>>(x, groups, out, G);
}